// Round 2
// baseline (103.245 us; speedup 1.0000x reference)
//
#include <hip/hip_runtime.h>

// HONU order-3: out[b] = sum_{i0<=i1<=i2} w[m(i0,i1,i2)] * xb[b,i0]*xb[b,i1]*xb[b,i2]
// xb = [1, x] (129 features). Weight index m computed analytically (lex order);
// comb_idx input ignored.
//
// R2 structure: i0-grouped (G=8). For fixed i1, 8 pairs share each x[i2] LDS read:
//   pacc[g] += w_g[i2] * x[i2]   (w wave-uniform -> SGPR, 1 LDS read per 8 FMAs)
//   accM += x[i0_g]*x[i1] * pacc[g]  at chunk close (linearity => partial runs OK)
// Work unit = one i2-step of one (i1, i0-chunk); TOTSTEPS steps split evenly
// over 1024 wave slots per batch tile -> near-exact static balance.

#define NF       129
#define NX       128
#define NCOMB    366145
#define TOTSTEPS 49521     // sum_i1 ceil((i1+1)/8)*(129-i1)
#define WSLOTS   1024
#define CH       49        // ceil(TOTSTEPS / WSLOTS)
#define G        8

__launch_bounds__(256, 4)
__global__ void honu_kernel(const float* __restrict__ x,
                            const float* __restrict__ weight,
                            float* __restrict__ out) {
    __shared__ float xbt[NF * 64];   // transposed: [feat][row]; bank = row mod 32 -> conflict-free
    __shared__ float red[256];

    const int tid  = threadIdx.x;
    const int lane = tid & 63;
    const int row0 = blockIdx.y * 64;

    // ---- stage x (64 rows x 128 feats) TRANSPOSED into LDS ----
    // thread (r = tid>>2, q = tid&3) loads row r's float4 columns q, q+4, ..., q+28
    // LDS writes: addr = feat*64 + r -> bank r mod 32; wave has 16 r-values x4 q -> ~4-way, cheap
    {
        const int r = tid >> 2;
        const int q = tid & 3;
        const float4* xv = (const float4*)(x + (size_t)(row0 + r) * NX);
        #pragma unroll
        for (int t = 0; t < 8; ++t) {
            const int c4 = q + 4 * t;          // float4 column 0..31
            float4 v = xv[c4];
            const int fc = 1 + c4 * 4;         // feature index (0 = bias)
            xbt[(fc + 0) * 64 + r] = v.x;
            xbt[(fc + 1) * 64 + r] = v.y;
            xbt[(fc + 2) * 64 + r] = v.z;
            xbt[(fc + 3) * 64 + r] = v.w;
        }
        if (tid < 64) xbt[tid] = 1.0f;         // bias feature
    }
    __syncthreads();

    float accM = 0.0f;

    // wave-uniform slot id (readfirstlane forces SALU/s_load codegen downstream)
    const int ws = __builtin_amdgcn_readfirstlane(blockIdx.x * 4 + (tid >> 6));
    int s0 = ws * CH;
    int s1 = s0 + CH; if (s1 > TOTSTEPS) s1 = TOTSTEPS;

    if (s0 < s1) {
        // ---- decode flat step s0 -> (i1, chunk c, i2) ----
        int i1 = 0, pref = 0;
        for (;;) {
            const int st = ((i1 + 8) >> 3) * (NF - i1);   // ceil((i1+1)/8)*(129-i1)
            if (pref + st > s0) break;
            pref += st; ++i1;
        }
        const int local0 = s0 - pref;
        const int len0   = NF - i1;
        int c  = local0 / len0;
        int i2 = i1 + (local0 - c * len0);

        int s = s0;
        while (s < s1) {
            const int i0b  = c * 8;
            const int n1   = NF - i1;
            const int c2n1 = (n1 * (n1 + 1)) >> 1;
            // weight pointers for the 8 pairs (i0b+g, i1); m(i0,i1,i2) = mbase + (i2-i1)
            const float* wp[G];
            #pragma unroll
            for (int g = 0; g < G; ++g) {
                int i0 = i0b + g;
                if (i0 > i1) i0 = i0b;            // dummy pair (discarded at fold)
                const int n0 = NF - i0;
                const int mb = NCOMB - (n0 * (n0 + 1) * (n0 + 2)) / 6
                                     + ((n0 * (n0 + 1)) >> 1) - c2n1;
                wp[g] = weight + (mb - i1);
            }

            int take = NF - i2;
            if (take > s1 - s) take = s1 - s;
            const int i2e = i2 + take;

            float pacc[G];
            #pragma unroll
            for (int g = 0; g < G; ++g) pacc[g] = 0.0f;

            #pragma unroll 4
            for (; i2 < i2e; ++i2) {
                const float xv = xbt[i2 * 64 + lane];   // 1 LDS read feeds 8 FMAs
                #pragma unroll
                for (int g = 0; g < G; ++g)
                    pacc[g] = fmaf(wp[g][i2], xv, pacc[g]);
            }
            s += take;

            // fold pair partials: accM += x[i0]*x[i1] * pacc[g]
            const float xi1 = xbt[i1 * 64 + lane];
            const int Gc = (i1 + 1 - i0b < G) ? (i1 + 1 - i0b) : G;
            #pragma unroll
            for (int g = 0; g < G; ++g)
                if (g < Gc)
                    accM = fmaf(xbt[(i0b + g) * 64 + lane] * xi1, pacc[g], accM);

            // advance to next unit
            if (i2 == NF) {
                ++c;
                if (8 * c > i1) { ++i1; c = 0; }   // chunks exhausted for this i1
                i2 = i1;
            }
        }
    }

    // ---- block reduce (4 waves) then one atomic per row ----
    red[tid] = accM;
    __syncthreads();
    if (tid < 64) {
        const float r2 = red[tid] + red[tid + 64] + red[tid + 128] + red[tid + 192];
        atomicAdd(&out[row0 + tid], r2);
    }
}

extern "C" void kernel_launch(void* const* d_in, const int* in_sizes, int n_in,
                              void* d_out, int out_size, void* d_ws, size_t ws_size,
                              hipStream_t stream) {
    const float* x      = (const float*)d_in[0];
    const float* weight = (const float*)d_in[1];
    // d_in[2] (comb_idx) unused: lex order computed analytically.
    float* out = (float*)d_out;

    hipMemsetAsync(out, 0, (size_t)out_size * sizeof(float), stream);
    dim3 grid(WSLOTS / 4, 256 / 64);   // 256 combo-blocks x 4 batch tiles, 4 waves/block
    honu_kernel<<<grid, 256, 0, stream>>>(x, weight, out);
}

// Round 3
// 96.380 us; speedup vs baseline: 1.0712x; 1.0712x over previous
//
#include <hip/hip_runtime.h>

// HONU order-3: out[b] = sum_{i0<=i1<=i2} w[m] * xb[b,i0]*xb[b,i1]*xb[b,i2], xb=[1,x].
// comb_idx is lex-ordered combinations_with_replacement -> m computed analytically;
// comb_idx input ignored.
//
// R3: each wave owns a CONTIGUOUS flat m-range (i2 fastest, then i1, then i0), so
// weights are consecutive -> s_load_dwordx16 into SGPRs (readfirstlane'd base),
// consumed as SGPR operand of v_fmac. Per combo: 1 ds_read_b32 + 1 v_fmac.
// Per-i1-run partial pacc folds with p01=x[i0]*x[i1] at run close (linearity).
// No atomics: partials -> d_ws[256][256], stage2 reduces and overwrites d_out.

#define NF     129
#define NX     128
#define NCOMB  366145
#define NBX    256              // combo-blocks per batch tile
#define WST    (NBX * 4)        // wave slots per tile
#define CHM    358              // ceil(NCOMB / WST)

__launch_bounds__(256, 4)
__global__ void honu_stage1(const float* __restrict__ x,
                            const float* __restrict__ weight,
                            float* __restrict__ ws) {
    __shared__ float xbt[NF * 64];   // transposed [feat][row]; read bank = lane%32 (2-way: free)
    __shared__ float red[256];
    const int tid  = threadIdx.x;
    const int lane = tid & 63;
    const int row0 = blockIdx.y * 64;

    // stage x (64 rows x 128 feats) transposed into LDS; coalesced float4 global loads
    {
        const int r = tid >> 2, q = tid & 3;
        const float4* xv = (const float4*)(x + (size_t)(row0 + r) * NX);
        #pragma unroll
        for (int t = 0; t < 8; ++t) {
            const int c4 = q + 4 * t;
            float4 v = xv[c4];
            const int fc = 1 + c4 * 4;
            xbt[(fc + 0) * 64 + r] = v.x;
            xbt[(fc + 1) * 64 + r] = v.y;
            xbt[(fc + 2) * 64 + r] = v.z;
            xbt[(fc + 3) * 64 + r] = v.w;
        }
        if (tid < 64) xbt[tid] = 1.0f;   // bias feature
    }
    __syncthreads();

    float acc = 0.0f;
    const int wslot = __builtin_amdgcn_readfirstlane(blockIdx.x * 4 + (tid >> 6));
    int s  = wslot * CHM;
    int s1 = s + CHM; if (s1 > NCOMB) s1 = NCOMB;

    if (s < s1) {
        // decode flat m=s -> (i0,i1,i2); prefix(i0) = NCOMB - T3(NF-i0)
        int i0 = 0;
        while (i0 < NX) { int n = NF - (i0 + 1); if (NCOMB - n*(n+1)*(n+2)/6 <= s) ++i0; else break; }
        int n0 = NF - i0;
        int r  = s - (NCOMB - n0*(n0+1)*(n0+2)/6);
        int t2 = (n0 * (n0 + 1)) >> 1;
        int i1 = i0;
        while (i1 < NX) { int n = NF - (i1 + 1); if (t2 - ((n*(n+1))>>1) <= r) ++i1; else break; }
        int n1 = NF - i1;
        int i2 = i1 + (r - (t2 - ((n1*(n1+1)) >> 1)));

        float xi0  = xbt[i0 * 64 + lane];
        float p01  = xi0 * xbt[i1 * 64 + lane];
        float pacc = 0.0f;
        const float* xp = &xbt[i2 * 64 + lane];

#define HONU_STEP(WV)                                                 \
        {                                                             \
            pacc = fmaf((WV), *xp, pacc);                             \
            xp += 64; ++i2;                                           \
            if (i2 == NF) {                                           \
                acc = fmaf(p01, pacc, acc); pacc = 0.0f;              \
                ++i1;                                                 \
                if (i1 >= NF) { ++i0; i1 = i0; }                      \
                if (i1 < NF) {                                        \
                    xi0 = xbt[i0 * 64 + lane];                        \
                    p01 = xi0 * xbt[i1 * 64 + lane];                  \
                    i2  = i1;                                         \
                    xp  = &xbt[i2 * 64 + lane];                       \
                }                                                     \
            }                                                         \
        }

        while (s + 16 <= s1) {
            const int mu = __builtin_amdgcn_readfirstlane(s);   // uniform -> s_load_dwordx16
            #pragma unroll
            for (int k = 0; k < 16; ++k) {
                const float w = weight[mu + k];
                HONU_STEP(w)
            }
            s += 16;
        }
        {
            const int mu  = __builtin_amdgcn_readfirstlane(s);
            const int rem = s1 - s;
            for (int k = 0; k < rem; ++k) {
                const float w = weight[mu + k];
                HONU_STEP(w)
            }
        }
        acc = fmaf(p01, pacc, acc);   // close open run (pacc=0 if none open)
#undef HONU_STEP
    }

    red[tid] = acc;
    __syncthreads();
    if (tid < 64) {
        const float v = red[tid] + red[tid + 64] + red[tid + 128] + red[tid + 192];
        ws[blockIdx.x * 256 + row0 + tid] = v;   // disjoint writes, no atomics
    }
}

__launch_bounds__(256, 1)
__global__ void honu_stage2(const float* __restrict__ ws, float* __restrict__ out) {
    const int r = threadIdx.x;
    float a0 = 0.f, a1 = 0.f, a2 = 0.f, a3 = 0.f;
    #pragma unroll 4
    for (int b = 0; b < NBX; b += 4) {
        a0 += ws[(b + 0) * 256 + r];
        a1 += ws[(b + 1) * 256 + r];
        a2 += ws[(b + 2) * 256 + r];
        a3 += ws[(b + 3) * 256 + r];
    }
    out[r] = (a0 + a1) + (a2 + a3);   // overwrites poison; no memset needed
}

extern "C" void kernel_launch(void* const* d_in, const int* in_sizes, int n_in,
                              void* d_out, int out_size, void* d_ws, size_t ws_size,
                              hipStream_t stream) {
    const float* x      = (const float*)d_in[0];
    const float* weight = (const float*)d_in[1];
    // d_in[2] (comb_idx) unused: lex order computed analytically.
    float* out = (float*)d_out;
    float* ws  = (float*)d_ws;      // needs 256*256*4 = 256 KB

    dim3 grid(NBX, 4);              // 256 combo-blocks x 4 batch tiles, 4 waves/block
    honu_stage1<<<grid, 256, 0, stream>>>(x, weight, ws);
    honu_stage2<<<1, 256, 0, stream>>>(ws, out);
}

// Round 4
// 94.627 us; speedup vs baseline: 1.0911x; 1.0185x over previous
//
#include <hip/hip_runtime.h>

// HONU order-3: out[b] = sum_{i0<=i1<=i2} w[m] * xb[b,i0]*xb[b,i1]*xb[b,i2], xb=[1,x].
// comb_idx is lex-ordered combinations_with_replacement -> m analytic; input ignored.
//
// R4: i0-grouped (G=8 pairs share each x[i2]); inner loop unrolled x4 over i2 with
// 16B weight loads per stream (8 independent loads in flight per 4 steps).
// 512-thread blocks (8 waves) x 35KB LDS -> 4 blocks/CU = 32 waves/CU (2x R2/R3).
// Partials -> d_ws[128][256] (disjoint), stage2 reduces. No atomics, no memset.

#define NF       129
#define NX       128
#define NCOMB    366145
#define TOTSTEPS 49521          // sum_i1 ceil((i1+1)/8)*(129-i1)
#define NBX      128            // combo-blocks per batch tile
#define WPB      8              // waves per block
#define WST      (NBX*WPB)      // 1024 wave slots per tile
#define CH       49             // ceil(TOTSTEPS / WST)

typedef float f4a4 __attribute__((ext_vector_type(4), aligned(4)));

__launch_bounds__(512, 8)
__global__ void honu_stage1(const float* __restrict__ x,
                            const float* __restrict__ weight,
                            float* __restrict__ ws) {
    __shared__ float xbt[NF * 64];   // transposed [feat][row]; inner reads: bank=lane%32, free
    __shared__ float red[512];
    const int tid  = threadIdx.x;
    const int lane = tid & 63;
    const int row0 = blockIdx.y * 64;

    // stage x (64 rows x 128 feats) transposed into LDS (coalesced float4 loads)
    {
        const int r = tid >> 3, q = tid & 7;
        const float4* xv = (const float4*)(x + (size_t)(row0 + r) * NX);
        #pragma unroll
        for (int t = 0; t < 4; ++t) {
            const int c4 = q + 8 * t;
            float4 v = xv[c4];
            const int fc = 1 + 4 * c4;
            xbt[(fc + 0) * 64 + r] = v.x;
            xbt[(fc + 1) * 64 + r] = v.y;
            xbt[(fc + 2) * 64 + r] = v.z;
            xbt[(fc + 3) * 64 + r] = v.w;
        }
        if (tid < 64) xbt[tid] = 1.0f;   // bias feature
    }
    __syncthreads();

    float acc = 0.0f;
    const int wslot = __builtin_amdgcn_readfirstlane(blockIdx.x * WPB + (tid >> 6));
    int s  = wslot * CH;
    int s1 = s + CH; if (s1 > TOTSTEPS) s1 = TOTSTEPS;

    if (s < s1) {
        // decode flat step s -> (i1, chunk c, i2)
        int i1 = 0, pref = 0;
        for (;;) {
            const int st = ((i1 + 8) >> 3) * (NF - i1);
            if (pref + st > s) break;
            pref += st; ++i1;
        }
        const int local = s - pref;
        const int len   = NF - i1;
        int c  = local / len;
        int i2 = i1 + (local - c * len);

        while (s < s1) {
            const int i0b  = c * 8;
            const int n1   = NF - i1;
            const int c2n1 = (n1 * (n1 + 1)) >> 1;
            const float* wp[8];               // uniform -> scalar regs
            #pragma unroll
            for (int g = 0; g < 8; ++g) {
                int i0 = i0b + g; if (i0 > i1) i0 = i0b;   // dummy (discarded at fold)
                const int n0 = NF - i0;
                const int mb = NCOMB - (n0 * (n0 + 1) * (n0 + 2)) / 6
                                     + ((n0 * (n0 + 1)) >> 1) - c2n1;
                wp[g] = weight + (mb - i1);   // wp[g][i2] = w(i0,i1,i2)
            }

            int take = NF - i2;
            const int room = s1 - s;
            if (take > room) take = room;
            const int i2e = i2 + take;

            float pacc[8];
            #pragma unroll
            for (int g = 0; g < 8; ++g) pacc[g] = 0.0f;

            const float* xp = &xbt[i2 * 64 + lane];

            // main: 4 i2-steps per iter, 8x 16B weight loads in flight
            for (; i2 + 4 <= i2e; i2 += 4) {
                const float x0 = xp[0], x1 = xp[64], x2 = xp[128], x3 = xp[192];
                xp += 256;
                #pragma unroll
                for (int g = 0; g < 8; ++g) {
                    f4a4 w4 = *(const f4a4*)(wp[g] + i2);
                    pacc[g] = fmaf(w4[0], x0, pacc[g]);
                    pacc[g] = fmaf(w4[1], x1, pacc[g]);
                    pacc[g] = fmaf(w4[2], x2, pacc[g]);
                    pacc[g] = fmaf(w4[3], x3, pacc[g]);
                }
            }
            for (; i2 < i2e; ++i2) {          // tail (<=3 steps)
                const float xv = *xp; xp += 64;
                #pragma unroll
                for (int g = 0; g < 8; ++g)
                    pacc[g] = fmaf(wp[g][i2], xv, pacc[g]);
            }
            s += take;

            // fold: acc += x[i0]*x[i1]*pacc (linearity => partial runs compose)
            const float xi1 = xbt[i1 * 64 + lane];
            int Gc = i1 + 1 - i0b; if (Gc > 8) Gc = 8;
            #pragma unroll
            for (int g = 0; g < 8; ++g)
                if (g < Gc)
                    acc = fmaf(xbt[(i0b + g) * 64 + lane] * xi1, pacc[g], acc);

            if (i2 == NF) {                   // unit finished -> next (i1, c)
                ++c;
                if (8 * c > i1) { ++i1; c = 0; }
                i2 = i1;
            }
        }
    }

    // block reduce (8 waves) -> disjoint partial per (block.x, row)
    red[tid] = acc;
    __syncthreads();
    if (tid < 64) {
        float v = 0.0f;
        #pragma unroll
        for (int wv = 0; wv < 8; ++wv) v += red[tid + wv * 64];
        ws[blockIdx.x * 256 + row0 + tid] = v;
    }
}

__launch_bounds__(1024, 1)
__global__ void honu_stage2(const float* __restrict__ ws, float* __restrict__ out) {
    __shared__ float red[1024];
    const int tid = threadIdx.x;
    const int r = tid & 255, q = tid >> 8;    // q = 0..3
    float a = 0.0f;
    #pragma unroll 8
    for (int j = 0; j < 32; ++j)
        a += ws[(q * 32 + j) * 256 + r];      // coalesced column sums
    red[tid] = a;
    __syncthreads();
    if (tid < 256)
        out[r] = (red[r] + red[r + 256]) + (red[r + 512] + red[r + 768]);
}

extern "C" void kernel_launch(void* const* d_in, const int* in_sizes, int n_in,
                              void* d_out, int out_size, void* d_ws, size_t ws_size,
                              hipStream_t stream) {
    const float* x      = (const float*)d_in[0];
    const float* weight = (const float*)d_in[1];
    // d_in[2] (comb_idx) unused: lex order computed analytically.
    float* out = (float*)d_out;
    float* ws  = (float*)d_ws;      // uses 128*256*4 = 128 KB

    dim3 grid(NBX, 4);              // 128 combo-blocks x 4 batch tiles, 8 waves/block
    honu_stage1<<<grid, 512, 0, stream>>>(x, weight, ws);
    honu_stage2<<<1, 1024, 0, stream>>>(ws, out);
}